// Round 11
// baseline (2963.002 us; speedup 1.0000x reference)
//
#include <hip/hip_runtime.h>

using f4_t  = __attribute__((ext_vector_type(4))) float;
using bf8_t = __attribute__((ext_vector_type(8))) short;
using u32x4 = __attribute__((ext_vector_type(4))) unsigned int;

#define T_DIM 512
#define B_DIM 256
#define I_DIM 256
#define H_DIM 1024
#define O_DIM 128

// XOR swizzle for GEMM tiles (T2 recipe)
#define SWZ(row, byte) ((byte) ^ (((row) & 7) << 4))
// hT swizzle: 4-bit row XOR -> 16 slots over 256B window
#define HSWZ(row, byte) ((byte) ^ (((row) & 15) << 4))

#define SMASK 0x8000800080008000ull  // bf16 sign bits of a 4-element qword

__device__ __forceinline__ unsigned short f2bf(float f) {
  unsigned u = __builtin_bit_cast(unsigned, f);
  return (unsigned short)((u + 0x7FFFu + ((u >> 16) & 1u)) >> 16);
}

__device__ __forceinline__ unsigned long long pack4bf(f4_t v) {
  unsigned long long r;
  r  = (unsigned long long)f2bf(v[0]);
  r |= (unsigned long long)f2bf(v[1]) << 16;
  r |= (unsigned long long)f2bf(v[2]) << 32;
  r |= (unsigned long long)f2bf(v[3]) << 48;
  return r;
}

// ---------------------------------------------------------------- init ------
__global__ __launch_bounds__(256, 1) void k_init(
    const float* __restrict__ Wi, const float* __restrict__ Wh,
    const float* __restrict__ Wo, unsigned short* __restrict__ Wi_b,
    unsigned short* __restrict__ Wh_b, unsigned short* __restrict__ Wo_b,
    unsigned short* __restrict__ hbuf1, unsigned* __restrict__ done) {
  int idx = blockIdx.x * 256 + threadIdx.x;
  int stride = gridDim.x * 256;
  for (int i = idx; i < H_DIM * H_DIM; i += stride) Wh_b[i] = f2bf(Wh[i]);
  for (int i = idx; i < H_DIM * I_DIM; i += stride) Wi_b[i] = f2bf(Wi[i]);
  for (int i = idx; i < O_DIM * H_DIM; i += stride) Wo_b[i] = f2bf(Wo[i]);
  for (int i = idx; i < B_DIM * H_DIM; i += stride) hbuf1[i] = 0x8000;
  for (int i = idx; i < 256 * 32; i += stride) done[i] = 0;
}

// --------------------------------------------------- phase 1: x @ Wi^T + bi -
__global__ __launch_bounds__(256, 2) void k_inproj(
    const float* __restrict__ x, const unsigned short* __restrict__ Wi_b,
    const float* __restrict__ bi, float* __restrict__ act) {
  __shared__ unsigned short As[128 * 128];
  __shared__ unsigned short Bs[128 * 128];
  int blk = blockIdx.x;
  int mb = (blk & 7) * 128 + (blk >> 6);
  int nb = (blk >> 3) & 7;
  int m0 = mb * 128, n0 = nb * 128;
  int tid = threadIdx.x;
  int lane = tid & 63, w = tid >> 6;
  int wm0 = (w & 1) * 64, wn0 = (w >> 1) * 64;
  int lrow = lane & 15, lk = (lane >> 4) * 8;
  f4_t acc[4][4];
#pragma unroll
  for (int a = 0; a < 4; ++a)
#pragma unroll
    for (int b = 0; b < 4; ++b) acc[a][b] = (f4_t){0.f, 0.f, 0.f, 0.f};

  for (int kb = 0; kb < 2; ++kb) {
    if (kb) __syncthreads();
#pragma unroll
    for (int it = 0; it < 16; ++it) {
      int c = it * 256 + tid;
      int row = c >> 5;
      int kc = (c & 31) * 4;
      f4_t v = *(const f4_t*)(x + (size_t)(m0 + row) * I_DIM + kb * 128 + kc);
      *(unsigned long long*)((char*)As + SWZ(row, row * 256 + kc * 2)) = pack4bf(v);
    }
#pragma unroll
    for (int it = 0; it < 8; ++it) {
      int c = it * 256 + tid;
      int row = c >> 4;
      int k16 = c & 15;
      u32x4 v = *(const u32x4*)(Wi_b + (size_t)(n0 + row) * I_DIM + kb * 128 + k16 * 8);
      *(u32x4*)((char*)Bs + SWZ(row, row * 256 + k16 * 16)) = v;
    }
    __syncthreads();
#pragma unroll
    for (int ks = 0; ks < 4; ++ks) {
      bf8_t aF[4], bF[4];
#pragma unroll
      for (int mt = 0; mt < 4; ++mt) {
        int row = wm0 + mt * 16 + lrow;
        aF[mt] = *(const bf8_t*)((char*)As + SWZ(row, row * 256 + (ks * 32 + lk) * 2));
      }
#pragma unroll
      for (int nt = 0; nt < 4; ++nt) {
        int row = wn0 + nt * 16 + lrow;
        bF[nt] = *(const bf8_t*)((char*)Bs + SWZ(row, row * 256 + (ks * 32 + lk) * 2));
      }
#pragma unroll
      for (int mt = 0; mt < 4; ++mt)
#pragma unroll
        for (int nt = 0; nt < 4; ++nt)
          acc[mt][nt] =
              __builtin_amdgcn_mfma_f32_16x16x32_bf16(aF[mt], bF[nt], acc[mt][nt], 0, 0, 0);
    }
  }
#pragma unroll
  for (int nt = 0; nt < 4; ++nt) {
    int col = n0 + wn0 + nt * 16 + lrow;
    float bv = bi[col];
#pragma unroll
    for (int mt = 0; mt < 4; ++mt) {
      int rbase = m0 + wm0 + mt * 16 + (lane >> 4) * 4;
#pragma unroll
      for (int r = 0; r < 4; ++r)
        act[(size_t)(rbase + r) * H_DIM + col] = acc[mt][nt][r] + bv;
    }
  }
}

// ------------------------------------------------------- phase 2: the scan --
// R11: TWO-CHAIN INTERLEAVE.  R10's null (halved chip txns, same time) pins
// the cost to the per-WG serial chain: poll -> 32KB fetch -> compute, nothing
// overlapped.  Batch groups are independent chains -> each WG now owns its
// h-slice for TWO groups (2p, 2p+1) and software-pipelines them:
//   [poll+issue B(t)] [process A(t)] [poll+issue A(t+1)] [process B(t)]
// Each chain's poll+fetch latency hides under the other chain's process
// phase.  Counted s_waitcnt vmcnt(4) = other chain's 4 just-issued loads
// (all other outstanding vmem is older; vmcnt retires in order -> safe).
// Protocol per chain unchanged from R10 (tags + hint flags + bounded retry).
__global__ __launch_bounds__(512, 1) void k_scan(
    const unsigned short* __restrict__ Wh_b, const float* __restrict__ bh,
    float* __restrict__ act, unsigned short* __restrict__ hbuf0,
    unsigned short* __restrict__ hbuf1, unsigned* __restrict__ done) {
  __shared__ __align__(16) char hTA[16 * 2048];
  __shared__ __align__(16) char hTB[16 * 2048];
  __shared__ __align__(16) float pbufA[4][16][132];
  __shared__ __align__(16) float pbufB[4][16][132];
  int blk = blockIdx.x;                // 64 blocks
  int pair = blk & 7, hs = blk >> 3;   // 8 pairs x 8 h-slices
  int gA = pair * 2, gB = pair * 2 + 1;
  int b0A = gA * 16, b0B = gB * 16, h0 = hs * 128;
  int tid = threadIdx.x;
  int lane = tid & 63, w = tid >> 6;   // 8 waves
  int nb = w & 1, ks = w >> 1;         // n-half, k-slice roles
  int lrow = lane & 15, lgq = lane >> 4;

  // persistent Wh fragments (shared by both chains: same h-cols, same K-slice)
  bf8_t Bf[4][8];
#pragma unroll
  for (int n = 0; n < 4; ++n)
#pragma unroll
    for (int kc = 0; kc < 8; ++kc)
      Bf[n][kc] = *(const bf8_t*)(Wh_b +
                                  (size_t)(h0 + nb * 64 + n * 16 + lrow) * H_DIM +
                                  ks * 256 + kc * 32 + lgq * 8);

  int pr = tid >> 5, pc = (tid & 31) * 4;  // pointwise: row pr, cols pc..pc+3
  float stA[4] = {0.f, 0.f, 0.f, 0.f};
  float stB[4] = {0.f, 0.f, 0.f, 0.f};
  f4_t bh4 = *(const f4_t*)(bh + h0 + pc);

  unsigned short* hb[2] = {hbuf0, hbuf1};
  unsigned* slotA = done + (gA * 8 + hs) * 32;
  unsigned* slotB = done + (gB * 8 + hs) * 32;
  const unsigned* pollA = done + (gA * 8 + (lane & 7)) * 32;
  const unsigned* pollB = done + (gB * 8 + (lane & 7)) * 32;
  bool dopoll = (lane < 8) && (lane != hs);

  f4_t uA = *(const f4_t*)(act + (size_t)(b0A + pr) * H_DIM + h0 + pc);
  f4_t uB = *(const f4_t*)(act + (size_t)(b0B + pr) * H_DIM + h0 + pc);

  int rh = tid >> 7;            // 0..3 (staging row within sweep)
  int colb = (tid & 127) * 16;  // staging byte col

  u32x4 qA0, qA1, qA2, qA3, qB0, qB1, qB2, qB3;
  unsigned long long aA, aB;

#define ISSUE4(q0_, q1_, q2_, q3_, a_)                                          \
  asm volatile("global_load_dwordx4 %[d0], %[a0], off sc0 sc1\n\t"              \
               "global_load_dwordx4 %[d1], %[a1], off sc0 sc1\n\t"              \
               "global_load_dwordx4 %[d2], %[a2], off sc0 sc1\n\t"              \
               "global_load_dwordx4 %[d3], %[a3], off sc0 sc1"                  \
               : [d0] "=&v"(q0_), [d1] "=&v"(q1_), [d2] "=&v"(q2_),             \
                 [d3] "=&v"(q3_)                                                \
               : [a0] "v"(a_), [a1] "v"(a_ + 8192), [a2] "v"(a_ + 16384),       \
                 [a3] "v"(a_ + 24576)                                           \
               : "memory")
#define STALEQ(qq, wnt) \
  ((((qq[0] ^ (wnt)) | (qq[1] ^ (wnt)) | (qq[2] ^ (wnt)) | (qq[3] ^ (wnt))) & \
    0x80008000u) != 0u)
#define RELOADQ(qq, ad)                                                         \
  asm volatile("global_load_dwordx4 %0, %1, off sc0 sc1\n\ts_waitcnt vmcnt(0)"  \
               : "=&v"(qq)                                                      \
               : "v"(ad)                                                        \
               : "memory")
#define VALIDATE4(q0_, q1_, q2_, q3_, a_, wnt)                                  \
  {                                                                             \
    int vg = 0;                                                                 \
    for (;;) {                                                                  \
      unsigned m = (STALEQ(q0_, wnt) ? 1u : 0u) | (STALEQ(q1_, wnt) ? 2u : 0u) |\
                   (STALEQ(q2_, wnt) ? 4u : 0u) | (STALEQ(q3_, wnt) ? 8u : 0u); \
      if (m == 0u || ++vg >= 400) break;                                        \
      __builtin_amdgcn_s_sleep(1);                                              \
      if (m & 1u) RELOADQ(q0_, a_);                                             \
      if (m & 2u) RELOADQ(q1_, a_ + 8192);                                      \
      if (m & 4u) RELOADQ(q2_, a_ + 16384);                                     \
      if (m & 8u) RELOADQ(q3_, a_ + 24576);                                     \
    }                                                                           \
    _Pragma("unroll") for (int d = 0; d < 4; ++d) {                             \
      q0_[d] &= 0x7fff7fffu; q1_[d] &= 0x7fff7fffu;                             \
      q2_[d] &= 0x7fff7fffu; q3_[d] &= 0x7fff7fffu;                             \
    }                                                                           \
  }
  // PROCESS one chain's step t: validate -> stage -> MFMA -> reduce ->
  // pointwise -> tagged h store -> flag -> act store (+u prefetch).
#define PROCESS(q0_, q1_, q2_, q3_, a_, hT_, pbuf_, st_, u_, b0_, slot_, wnt)   \
  {                                                                             \
    asm volatile("s_waitcnt vmcnt(4)" ::: "memory");                            \
    __builtin_amdgcn_sched_barrier(0);                                          \
    VALIDATE4(q0_, q1_, q2_, q3_, a_, wnt);                                     \
    *(u32x4*)(&hT_[(0 * 4 + rh) * 2048 + HSWZ(0 * 4 + rh, colb)]) = q0_;        \
    *(u32x4*)(&hT_[(1 * 4 + rh) * 2048 + HSWZ(1 * 4 + rh, colb)]) = q1_;        \
    *(u32x4*)(&hT_[(2 * 4 + rh) * 2048 + HSWZ(2 * 4 + rh, colb)]) = q2_;        \
    *(u32x4*)(&hT_[(3 * 4 + rh) * 2048 + HSWZ(3 * 4 + rh, colb)]) = q3_;        \
    asm volatile("s_waitcnt lgkmcnt(0)\ns_barrier" ::: "memory");               \
    __builtin_amdgcn_sched_barrier(0);                                          \
    f4_t acc[4];                                                                \
    _Pragma("unroll") for (int n = 0; n < 4; ++n)                               \
        acc[n] = (f4_t){0.f, 0.f, 0.f, 0.f};                                    \
    _Pragma("unroll") for (int kc = 0; kc < 8; ++kc) {                          \
      int cbyte = ks * 512 + kc * 64 + lgq * 16;                                \
      bf8_t Af = *(const bf8_t*)(&hT_[lrow * 2048 + HSWZ(lrow, cbyte)]);        \
      _Pragma("unroll") for (int n = 0; n < 4; ++n)                             \
          acc[n] =                                                              \
              __builtin_amdgcn_mfma_f32_16x16x32_bf16(Af, Bf[n][kc], acc[n], 0, 0, 0); \
    }                                                                           \
    _Pragma("unroll") for (int n = 0; n < 4; ++n) _Pragma("unroll")             \
        for (int r = 0; r < 4; ++r)                                             \
            pbuf_[ks][lgq * 4 + r][nb * 64 + n * 16 + lrow] = acc[n][r];        \
    asm volatile("s_waitcnt lgkmcnt(0)\ns_barrier" ::: "memory");               \
    __builtin_amdgcn_sched_barrier(0);                                          \
    f4_t s0 = *(const f4_t*)&pbuf_[0][pr][pc];                                  \
    f4_t s1 = *(const f4_t*)&pbuf_[1][pr][pc];                                  \
    f4_t s2 = *(const f4_t*)&pbuf_[2][pr][pc];                                  \
    f4_t s3 = *(const f4_t*)&pbuf_[3][pr][pc];                                  \
    f4_t tot = s0 + s1 + s2 + s3 + u_ + bh4;                                    \
    f4_t hres;                                                                  \
    _Pragma("unroll") for (int j = 0; j < 4; ++j) {                             \
      st_[j] = st_[j] * 0.8f + tot[j] * 0.2f;                                   \
      hres[j] = fmaxf(st_[j], 0.f);                                             \
    }                                                                           \
    unsigned long long hp = pack4bf(hres) | (((t >> 1) & 1) ? SMASK : 0ull);    \
    unsigned long long sa =                                                     \
        (unsigned long long)(hb[p] + (size_t)(b0_ + pr) * H_DIM + h0 + pc);     \
    asm volatile("global_store_dwordx2 %0, %1, off sc0 sc1" ::"v"(sa), "v"(hp)  \
                 : "memory");                                                   \
    asm volatile("s_barrier" ::: "memory");                                     \
    if (tid == 0)                                                               \
      __hip_atomic_store(slot_, (unsigned)(t + 1), __ATOMIC_RELAXED,            \
                         __HIP_MEMORY_SCOPE_AGENT);                             \
    *(f4_t*)(act + ((size_t)t * B_DIM + b0_ + pr) * H_DIM + h0 + pc) = hres;    \
    int tn = (t + 1 < T_DIM) ? t + 1 : t;                                       \
    u_ = *(const f4_t*)(act + ((size_t)tn * B_DIM + b0_ + pr) * H_DIM + h0 + pc); \
  }

  // prologue: issue A(0) loads (hb[1] is init-tagged)
  aA = (unsigned long long)((const char*)(hb[1] + (size_t)b0A * H_DIM) + tid * 16);
  ISSUE4(qA0, qA1, qA2, qA3, aA);

  for (int t = 0; t < T_DIM; ++t) {
    int p = t & 1;
    unsigned want32 = ((((unsigned)(t - 1) >> 1) & 1u) ? 0x80008000u : 0u);

    // ---- phase 1: poll + issue B(t)
    if (t > 0 && dopoll) {
      int gd = 0;
      while (__hip_atomic_load(pollB, __ATOMIC_RELAXED, __HIP_MEMORY_SCOPE_AGENT) <
                 (unsigned)t &&
             ++gd < 60000)
        __builtin_amdgcn_s_sleep(1);
    }
    __builtin_amdgcn_sched_barrier(0);
    aB = (unsigned long long)((const char*)(hb[p ^ 1] + (size_t)b0B * H_DIM) + tid * 16);
    ISSUE4(qB0, qB1, qB2, qB3, aB);

    // ---- phase 2: process A(t)  (A's fetch was covered by prev iter's B-process)
    PROCESS(qA0, qA1, qA2, qA3, aA, hTA, pbufA, stA, uA, b0A, slotA, want32);

    // ---- phase 3: poll + issue A(t+1)
    if (t + 1 < T_DIM) {
      if (dopoll) {
        int gd = 0;
        while (__hip_atomic_load(pollA, __ATOMIC_RELAXED, __HIP_MEMORY_SCOPE_AGENT) <
                   (unsigned)(t + 1) &&
               ++gd < 60000)
          __builtin_amdgcn_s_sleep(1);
      }
      __builtin_amdgcn_sched_barrier(0);
      aA = (unsigned long long)((const char*)(hb[p] + (size_t)b0A * H_DIM) + tid * 16);
      ISSUE4(qA0, qA1, qA2, qA3, aA);
    }

    // ---- phase 4: process B(t)  (B's fetch covered by phase 2)
    PROCESS(qB0, qB1, qB2, qB3, aB, hTB, pbufB, stB, uB, b0B, slotB, want32);
  }
#undef ISSUE4
#undef STALEQ
#undef RELOADQ
#undef VALIDATE4
#undef PROCESS
}

// ------------------------------------------------- phase 3: act @ Wo^T + bo -
__global__ __launch_bounds__(256, 2) void k_outproj(
    const float* __restrict__ act, const unsigned short* __restrict__ Wo_b,
    const float* __restrict__ bo, float* __restrict__ out) {
  __shared__ unsigned short As[128 * 64];
  __shared__ unsigned short Bs[128 * 64];
  int m0 = blockIdx.x * 128;
  int tid = threadIdx.x;
  int lane = tid & 63, w = tid >> 6;
  int wm0 = (w & 1) * 64, wn0 = (w >> 1) * 64;
  int lrow = lane & 15, lk = (lane >> 4) * 8;
  f4_t acc[4][4];
#pragma unroll
  for (int a = 0; a < 4; ++a)
#pragma unroll
    for (int b = 0; b < 4; ++b) acc[a][b] = (f4_t){0.f, 0.f, 0.f, 0.f};

  for (int kb = 0; kb < 16; ++kb) {
    if (kb) __syncthreads();
#pragma unroll
    for (int it = 0; it < 8; ++it) {
      int c = it * 256 + tid;
      int row = c >> 4;
      int kc = (c & 15) * 4;
      f4_t v = *(const f4_t*)(act + (size_t)(m0 + row) * H_DIM + kb * 64 + kc);
      *(unsigned long long*)((char*)As + SWZ(row, row * 128 + kc * 2)) = pack4bf(v);
    }
#pragma unroll
    for (int it = 0; it < 4; ++it) {
      int c = it * 256 + tid;
      int row = c >> 3;
      int k16 = c & 7;
      u32x4 v = *(const u32x4*)(Wo_b + (size_t)row * H_DIM + kb * 64 + k16 * 8);
      *(u32x4*)((char*)Bs + SWZ(row, row * 128 + k16 * 16)) = v;
    }
    __syncthreads();
#pragma unroll
    for (int ks = 0; ks < 2; ++ks) {
      bf8_t aF[4], bF[4];
#pragma unroll
      for (int mt = 0; mt < 4; ++mt) {
        int row = wm0 + mt * 16 + lrow;
        aF[mt] = *(const bf8_t*)((char*)As + SWZ(row, row * 128 + (ks * 32 + lk) * 2));
      }
#pragma unroll
      for (int nt = 0; nt < 4; ++nt) {
        int row = wn0 + nt * 16 + lrow;
        bF[nt] = *(const bf8_t*)((char*)Bs + SWZ(row, row * 128 + (ks * 32 + lk) * 2));
      }
#pragma unroll
      for (int mt = 0; mt < 4; ++mt)
#pragma unroll
        for (int nt = 0; nt < 4; ++nt)
          acc[mt][nt] =
              __builtin_amdgcn_mfma_f32_16x16x32_bf16(aF[mt], bF[nt], acc[mt][nt], 0, 0, 0);
    }
  }
#pragma unroll
  for (int nt = 0; nt < 4; ++nt) {
    int col = wn0 + nt * 16 + lrow;
    float bv = bo[col];
#pragma unroll
    for (int mt = 0; mt < 4; ++mt) {
      int rbase = m0 + wm0 + mt * 16 + (lane >> 4) * 4;
#pragma unroll
      for (int r = 0; r < 4; ++r)
        out[(size_t)(rbase + r) * O_DIM + col] = acc[mt][nt][r] + bv;
    }
  }
}

// ---------------------------------------------------------------------------
extern "C" void kernel_launch(void* const* d_in, const int* in_sizes, int n_in,
                              void* d_out, int out_size, void* d_ws, size_t ws_size,
                              hipStream_t stream) {
  const float* x  = (const float*)d_in[0];
  const float* Wi = (const float*)d_in[1];
  const float* bi = (const float*)d_in[2];
  const float* Wh = (const float*)d_in[3];
  const float* bh = (const float*)d_in[4];
  const float* Wo = (const float*)d_in[5];
  const float* bo = (const float*)d_in[6];

  float* out = (float*)d_out;                                  // [T,B,O]
  float* act = out + (size_t)T_DIM * B_DIM * O_DIM;            // [T,B,H]

  char* ws = (char*)d_ws;
  unsigned short* Wh_b  = (unsigned short*)(ws);                               // 2 MB
  unsigned short* Wi_b  = (unsigned short*)(ws + (2u << 20));                  // 512 KB
  unsigned short* Wo_b  = (unsigned short*)(ws + (2u << 20) + (512u << 10));   // 256 KB
  unsigned short* hbuf0 = (unsigned short*)(ws + (2u << 20) + (768u << 10));   // 512 KB
  unsigned short* hbuf1 = (unsigned short*)(ws + (2u << 20) + (1280u << 10));  // 512 KB
  unsigned* done        = (unsigned*)(ws + (2u << 20) + (1792u << 10));        // 32 KB

  k_init<<<1024, 256, 0, stream>>>(Wi, Wh, Wo, Wi_b, Wh_b, Wo_b, hbuf1, done);
  k_inproj<<<8192, 256, 0, stream>>>(x, Wi_b, bi, act);
  k_scan<<<64, 512, 0, stream>>>(Wh_b, bh, act, hbuf0, hbuf1, done);
  k_outproj<<<1024, 256, 0, stream>>>(act, Wo_b, bo, out);
}

// Round 12
// 2272.112 us; speedup vs baseline: 1.3041x; 1.3041x over previous
//
#include <hip/hip_runtime.h>

using f4_t  = __attribute__((ext_vector_type(4))) float;
using bf8_t = __attribute__((ext_vector_type(8))) short;
using u32x4 = __attribute__((ext_vector_type(4))) unsigned int;

#define T_DIM 512
#define B_DIM 256
#define I_DIM 256
#define H_DIM 1024
#define O_DIM 128

// XOR swizzle for GEMM tiles (T2 recipe)
#define SWZ(row, byte) ((byte) ^ (((row) & 7) << 4))
// hT swizzle: 4-bit row XOR (R10-proven: 0 bank conflicts)
#define HSWZ(row, byte) ((byte) ^ (((row) & 15) << 4))

#define SMASK 0x8000800080008000ull  // bf16 sign bits of a 4-element qword

__device__ __forceinline__ unsigned short f2bf(float f) {
  unsigned u = __builtin_bit_cast(unsigned, f);
  return (unsigned short)((u + 0x7FFFu + ((u >> 16) & 1u)) >> 16);
}

__device__ __forceinline__ unsigned long long pack4bf(f4_t v) {
  unsigned long long r;
  r  = (unsigned long long)f2bf(v[0]);
  r |= (unsigned long long)f2bf(v[1]) << 16;
  r |= (unsigned long long)f2bf(v[2]) << 32;
  r |= (unsigned long long)f2bf(v[3]) << 48;
  return r;
}

// ---------------------------------------------------------------- init ------
__global__ __launch_bounds__(256, 1) void k_init(
    const float* __restrict__ Wi, const float* __restrict__ Wh,
    const float* __restrict__ Wo, unsigned short* __restrict__ Wi_b,
    unsigned short* __restrict__ Wh_b, unsigned short* __restrict__ Wo_b,
    unsigned short* __restrict__ hbuf1, unsigned* __restrict__ done) {
  int idx = blockIdx.x * 256 + threadIdx.x;
  int stride = gridDim.x * 256;
  for (int i = idx; i < H_DIM * H_DIM; i += stride) Wh_b[i] = f2bf(Wh[i]);
  for (int i = idx; i < H_DIM * I_DIM; i += stride) Wi_b[i] = f2bf(Wi[i]);
  for (int i = idx; i < O_DIM * H_DIM; i += stride) Wo_b[i] = f2bf(Wo[i]);
  for (int i = idx; i < B_DIM * H_DIM; i += stride) hbuf1[i] = 0x8000;
  for (int i = idx; i < 256 * 32; i += stride) done[i] = 0;
}

// --------------------------------------------------- phase 1: x @ Wi^T + bi -
__global__ __launch_bounds__(256, 2) void k_inproj(
    const float* __restrict__ x, const unsigned short* __restrict__ Wi_b,
    const float* __restrict__ bi, float* __restrict__ act) {
  __shared__ unsigned short As[128 * 128];
  __shared__ unsigned short Bs[128 * 128];
  int blk = blockIdx.x;
  int mb = (blk & 7) * 128 + (blk >> 6);
  int nb = (blk >> 3) & 7;
  int m0 = mb * 128, n0 = nb * 128;
  int tid = threadIdx.x;
  int lane = tid & 63, w = tid >> 6;
  int wm0 = (w & 1) * 64, wn0 = (w >> 1) * 64;
  int lrow = lane & 15, lk = (lane >> 4) * 8;
  f4_t acc[4][4];
#pragma unroll
  for (int a = 0; a < 4; ++a)
#pragma unroll
    for (int b = 0; b < 4; ++b) acc[a][b] = (f4_t){0.f, 0.f, 0.f, 0.f};

  for (int kb = 0; kb < 2; ++kb) {
    if (kb) __syncthreads();
#pragma unroll
    for (int it = 0; it < 16; ++it) {
      int c = it * 256 + tid;
      int row = c >> 5;
      int kc = (c & 31) * 4;
      f4_t v = *(const f4_t*)(x + (size_t)(m0 + row) * I_DIM + kb * 128 + kc);
      *(unsigned long long*)((char*)As + SWZ(row, row * 256 + kc * 2)) = pack4bf(v);
    }
#pragma unroll
    for (int it = 0; it < 8; ++it) {
      int c = it * 256 + tid;
      int row = c >> 4;
      int k16 = c & 15;
      u32x4 v = *(const u32x4*)(Wi_b + (size_t)(n0 + row) * I_DIM + kb * 128 + k16 * 8);
      *(u32x4*)((char*)Bs + SWZ(row, row * 256 + k16 * 16)) = v;
    }
    __syncthreads();
#pragma unroll
    for (int ks = 0; ks < 4; ++ks) {
      bf8_t aF[4], bF[4];
#pragma unroll
      for (int mt = 0; mt < 4; ++mt) {
        int row = wm0 + mt * 16 + lrow;
        aF[mt] = *(const bf8_t*)((char*)As + SWZ(row, row * 256 + (ks * 32 + lk) * 2));
      }
#pragma unroll
      for (int nt = 0; nt < 4; ++nt) {
        int row = wn0 + nt * 16 + lrow;
        bF[nt] = *(const bf8_t*)((char*)Bs + SWZ(row, row * 256 + (ks * 32 + lk) * 2));
      }
#pragma unroll
      for (int mt = 0; mt < 4; ++mt)
#pragma unroll
        for (int nt = 0; nt < 4; ++nt)
          acc[mt][nt] =
              __builtin_amdgcn_mfma_f32_16x16x32_bf16(aF[mt], bF[nt], acc[mt][nt], 0, 0, 0);
    }
  }
#pragma unroll
  for (int nt = 0; nt < 4; ++nt) {
    int col = n0 + wn0 + nt * 16 + lrow;
    float bv = bi[col];
#pragma unroll
    for (int mt = 0; mt < 4; ++mt) {
      int rbase = m0 + wm0 + mt * 16 + (lane >> 4) * 4;
#pragma unroll
      for (int r = 0; r < 4; ++r)
        act[(size_t)(rbase + r) * H_DIM + col] = acc[mt][nt][r] + bv;
    }
  }
}

// ------------------------------------------------------- phase 2: the scan --
// R12 = exact R9 skeleton (1198us, best) + L2-served fetch fast path.
//  - Stores UNCHANGED (sc0 sc1 write-through to IC, R9-proven).
//  - Fast mode: first-try bulk loads are sc0-ONLY (may hit the XCD-local L2
//    copy filled by the first reader's miss -> 15/16 WGs read at L2 latency).
//    ALL retries use sc0 sc1 (IC) -> progress guaranteed even if L2 serves
//    stale lines; tags detect staleness (stale line = opposite-parity tag;
//    cross-replay same-tag hazard covered by the probe's invalidation test
//    and k_init's rewrite of hbuf1).
//  - One-time 2-round token probe per group decides fast/slow: round 1
//    detects stale-L2-across-replay, round 2 detects missing invalidation-on-
//    store.  Verdicts exchanged via proven IC atomics; any failure -> exact
//    R9 behavior (plus ~25us probe overhead).
__global__ __launch_bounds__(256, 1) void k_scan(
    const unsigned short* __restrict__ Wh_b, const float* __restrict__ bh,
    float* __restrict__ act, unsigned short* __restrict__ hbuf0,
    unsigned short* __restrict__ hbuf1, unsigned* __restrict__ done) {
  __shared__ __align__(16) char hT[16 * 2048];     // staged h(t-1)
  __shared__ __align__(16) float pbuf[4][16][68];  // K-partials
  __shared__ unsigned wcap[4];
  int blk = blockIdx.x;
  int g = blk & 15, hs = blk >> 4;
  int b0 = g * 16, h0 = hs * 64;
  int tid = threadIdx.x;
  int lane = tid & 63, w = tid >> 6;
  int lrow = lane & 15, lgq = lane >> 4, lk = lgq * 8;

  // persistent Wh fragments: [n-tile][k-chunk], K-slice = w*256..w*256+255
  bf8_t Bf[4][8];
#pragma unroll
  for (int n = 0; n < 4; ++n)
#pragma unroll
    for (int kc = 0; kc < 8; ++kc)
      Bf[n][kc] = *(const bf8_t*)(Wh_b + (size_t)(h0 + n * 16 + lrow) * H_DIM +
                                  w * 256 + kc * 32 + lk);

  int pr = tid >> 4, pc = (tid & 15) * 4;
  float st[4] = {0.f, 0.f, 0.f, 0.f};
  f4_t bh4 = *(const f4_t*)(bh + h0 + pc);

  unsigned short* hb[2] = {hbuf0, hbuf1};
  unsigned* myslot = done + (g * 16 + hs) * 32;        // [0]=flag [8]=probe [9]=verdict
  const unsigned* pollp = done + (g * 16 + (lane & 15)) * 32;
  bool dopoll = (lane < 16) && (lane != hs);

  // ---------------- one-time L2-visibility probe ----------------
  bool fast;
  {
    bool ok1 = true, ok2 = true;
    if (tid == 0) {
      unsigned tk = 0xA5000000u | (unsigned)blk;
      asm volatile("global_store_dword %0, %1, off sc0 sc1" ::"v"(
                       (unsigned long long)(myslot + 8)),
                   "v"(tk)
                   : "memory");
    }
    if (lane < 16) {
      const unsigned* ps = done + (g * 16 + lane) * 32 + 8;
      unsigned expect = 0xA5000000u | (unsigned)(g + 16 * lane);
      unsigned v = 0;
      int gd = 0;
      do {
        asm volatile("global_load_dword %0, %1, off sc0\n\ts_waitcnt vmcnt(0)"
                     : "=&v"(v)
                     : "v"((unsigned long long)ps)
                     : "memory");
        if (v == expect) break;
        __builtin_amdgcn_s_sleep(1);
      } while (++gd < 4000);
      ok1 = (v == expect);
    }
    // settle: let every WG's consumers finish round 1 before tokens change
    for (int i = 0; i < 100; ++i) __builtin_amdgcn_s_sleep(7);
    __syncthreads();
    if (tid == 0) {
      unsigned tk = 0x5A000000u | (unsigned)blk;
      asm volatile("global_store_dword %0, %1, off sc0 sc1" ::"v"(
                       (unsigned long long)(myslot + 8)),
                   "v"(tk)
                   : "memory");
    }
    if (lane < 16) {
      const unsigned* ps = done + (g * 16 + lane) * 32 + 8;
      unsigned expect = 0x5A000000u | (unsigned)(g + 16 * lane);
      unsigned v = 0;
      int gd = 0;
      do {
        asm volatile("global_load_dword %0, %1, off sc0\n\ts_waitcnt vmcnt(0)"
                     : "=&v"(v)
                     : "v"((unsigned long long)ps)
                     : "memory");
        if (v == expect) break;
        __builtin_amdgcn_s_sleep(1);
      } while (++gd < 4000);
      ok2 = (v == expect);
    }
    unsigned bl = __ballot(ok1 && ok2);
    if (lane == 0) wcap[w] = (bl == ~0ull) ? 1u : 0u;
    __syncthreads();
    bool cap = wcap[0] && wcap[1] && wcap[2] && wcap[3];
    if (tid == 0)
      __hip_atomic_store(myslot + 9, cap ? 2u : 1u, __ATOMIC_RELAXED,
                         __HIP_MEMORY_SCOPE_AGENT);
    bool vok = true;
    if (lane < 16) {
      const unsigned* vs = done + (g * 16 + lane) * 32 + 9;
      unsigned v = 0;
      long gd = 0;
      do {
        v = __hip_atomic_load(vs, __ATOMIC_RELAXED, __HIP_MEMORY_SCOPE_AGENT);
        if (v) break;
        __builtin_amdgcn_s_sleep(1);
      } while (++gd < 2000000L);
      vok = (v == 2u);
    }
    bl = __ballot(vok);
    __syncthreads();  // wcap WAR
    if (lane == 0) wcap[w] = (bl == ~0ull) ? 1u : 0u;
    __syncthreads();
    fast = wcap[0] && wcap[1] && wcap[2] && wcap[3];
  }

  // prefetch u for t=0
  f4_t ucur = *(const f4_t*)(act + (size_t)(b0 + pr) * H_DIM + h0 + pc);

#define RELOAD(qq, ad)                                                          \
  asm volatile("global_load_dwordx4 %0, %1, off sc0 sc1\n\ts_waitcnt vmcnt(0)"  \
               : "=&v"(qq)                                                      \
               : "v"(ad)                                                        \
               : "memory")
#define STALE(qq) \
  ((((qq[0] ^ want32) | (qq[1] ^ want32) | (qq[2] ^ want32) | (qq[3] ^ want32)) & \
    0x80008000u) != 0u)

#define SCAN_STEP(LOADSUF)                                                      \
  {                                                                             \
    int p = t & 1;                                                              \
    const unsigned short* hprev = hb[p ^ 1];                                    \
    unsigned want32 = ((((unsigned)(t - 1) >> 1) & 1u) ? 0x80008000u : 0u);     \
    if (t > 0 && dopoll) {                                                      \
      int gd = 0;                                                               \
      while (__hip_atomic_load(pollp, __ATOMIC_RELAXED,                         \
                               __HIP_MEMORY_SCOPE_AGENT) < (unsigned)t &&       \
             ++gd < 60000)                                                      \
        __builtin_amdgcn_s_sleep(1);                                            \
    }                                                                           \
    __builtin_amdgcn_sched_barrier(0);                                          \
    const char* base = (const char*)(hprev + (size_t)b0 * H_DIM);               \
    unsigned long long a0 = (unsigned long long)(base + tid * 16);              \
    u32x4 q0, q1, q2, q3, q4, q5, q6, q7;                                       \
    asm volatile(                                                               \
        "global_load_dwordx4 %[d0], %[a0], off " LOADSUF "\n\t"                 \
        "global_load_dwordx4 %[d1], %[a1], off " LOADSUF "\n\t"                 \
        "global_load_dwordx4 %[d2], %[a2], off " LOADSUF "\n\t"                 \
        "global_load_dwordx4 %[d3], %[a3], off " LOADSUF "\n\t"                 \
        "global_load_dwordx4 %[d4], %[a4], off " LOADSUF "\n\t"                 \
        "global_load_dwordx4 %[d5], %[a5], off " LOADSUF "\n\t"                 \
        "global_load_dwordx4 %[d6], %[a6], off " LOADSUF "\n\t"                 \
        "global_load_dwordx4 %[d7], %[a7], off " LOADSUF "\n\t"                 \
        "s_waitcnt vmcnt(0)"                                                    \
        : [d0] "=&v"(q0), [d1] "=&v"(q1), [d2] "=&v"(q2), [d3] "=&v"(q3),       \
          [d4] "=&v"(q4), [d5] "=&v"(q5), [d6] "=&v"(q6), [d7] "=&v"(q7)        \
        : [a0] "v"(a0), [a1] "v"(a0 + 4096), [a2] "v"(a0 + 8192),               \
          [a3] "v"(a0 + 12288), [a4] "v"(a0 + 16384), [a5] "v"(a0 + 20480),     \
          [a6] "v"(a0 + 24576), [a7] "v"(a0 + 28672)                            \
        : "memory");                                                            \
    __builtin_amdgcn_sched_barrier(0);                                          \
    int tn = (t + 1 < T_DIM) ? t + 1 : t;                                       \
    f4_t unext =                                                                \
        *(const f4_t*)(act + ((size_t)tn * B_DIM + b0 + pr) * H_DIM + h0 + pc); \
    {                                                                           \
      int vg = 0;                                                               \
      for (;;) {                                                                \
        unsigned m = (STALE(q0) ? 1u : 0u) | (STALE(q1) ? 2u : 0u) |            \
                     (STALE(q2) ? 4u : 0u) | (STALE(q3) ? 8u : 0u) |            \
                     (STALE(q4) ? 16u : 0u) | (STALE(q5) ? 32u : 0u) |          \
                     (STALE(q6) ? 64u : 0u) | (STALE(q7) ? 128u : 0u);          \
        if (m == 0u || ++vg >= 400) break;                                      \
        __builtin_amdgcn_s_sleep(1);                                            \
        if (m & 1u) RELOAD(q0, a0);                                             \
        if (m & 2u) RELOAD(q1, a0 + 4096);                                      \
        if (m & 4u) RELOAD(q2, a0 + 8192);                                      \
        if (m & 8u) RELOAD(q3, a0 + 12288);                                     \
        if (m & 16u) RELOAD(q4, a0 + 16384);                                    \
        if (m & 32u) RELOAD(q5, a0 + 20480);                                    \
        if (m & 64u) RELOAD(q6, a0 + 24576);                                    \
        if (m & 128u) RELOAD(q7, a0 + 28672);                                   \
      }                                                                         \
    }                                                                           \
    _Pragma("unroll") for (int d = 0; d < 4; ++d) {                             \
      q0[d] &= 0x7fff7fffu; q1[d] &= 0x7fff7fffu; q2[d] &= 0x7fff7fffu;         \
      q3[d] &= 0x7fff7fffu; q4[d] &= 0x7fff7fffu; q5[d] &= 0x7fff7fffu;         \
      q6[d] &= 0x7fff7fffu; q7[d] &= 0x7fff7fffu;                               \
    }                                                                           \
    {                                                                           \
      int rh = tid >> 7;                                                        \
      int colb = (tid & 127) * 16;                                              \
      *(u32x4*)(&hT[(0 + rh) * 2048 + HSWZ(0 + rh, colb)]) = q0;                \
      *(u32x4*)(&hT[(2 + rh) * 2048 + HSWZ(2 + rh, colb)]) = q1;                \
      *(u32x4*)(&hT[(4 + rh) * 2048 + HSWZ(4 + rh, colb)]) = q2;                \
      *(u32x4*)(&hT[(6 + rh) * 2048 + HSWZ(6 + rh, colb)]) = q3;                \
      *(u32x4*)(&hT[(8 + rh) * 2048 + HSWZ(8 + rh, colb)]) = q4;                \
      *(u32x4*)(&hT[(10 + rh) * 2048 + HSWZ(10 + rh, colb)]) = q5;              \
      *(u32x4*)(&hT[(12 + rh) * 2048 + HSWZ(12 + rh, colb)]) = q6;              \
      *(u32x4*)(&hT[(14 + rh) * 2048 + HSWZ(14 + rh, colb)]) = q7;              \
    }                                                                           \
    asm volatile("s_waitcnt lgkmcnt(0)\ns_barrier" ::: "memory");               \
    __builtin_amdgcn_sched_barrier(0);                                          \
    f4_t acc[4];                                                                \
    _Pragma("unroll") for (int n = 0; n < 4; ++n)                               \
        acc[n] = (f4_t){0.f, 0.f, 0.f, 0.f};                                    \
    _Pragma("unroll") for (int kc = 0; kc < 8; ++kc) {                          \
      int cbyte = w * 512 + kc * 64 + lgq * 16;                                 \
      bf8_t Af = *(const bf8_t*)(&hT[lrow * 2048 + HSWZ(lrow, cbyte)]);         \
      _Pragma("unroll") for (int n = 0; n < 4; ++n)                             \
          acc[n] = __builtin_amdgcn_mfma_f32_16x16x32_bf16(Af, Bf[n][kc],       \
                                                           acc[n], 0, 0, 0);    \
    }                                                                           \
    _Pragma("unroll") for (int n = 0; n < 4; ++n) _Pragma("unroll")             \
        for (int r = 0; r < 4; ++r)                                             \
            pbuf[w][lgq * 4 + r][n * 16 + lrow] = acc[n][r];                    \
    asm volatile("s_waitcnt lgkmcnt(0)\ns_barrier" ::: "memory");               \
    __builtin_amdgcn_sched_barrier(0);                                          \
    f4_t s0 = *(const f4_t*)&pbuf[0][pr][pc];                                   \
    f4_t s1 = *(const f4_t*)&pbuf[1][pr][pc];                                   \
    f4_t s2 = *(const f4_t*)&pbuf[2][pr][pc];                                   \
    f4_t s3 = *(const f4_t*)&pbuf[3][pr][pc];                                   \
    f4_t tot = s0 + s1 + s2 + s3 + ucur + bh4;                                  \
    f4_t hres;                                                                  \
    _Pragma("unroll") for (int j = 0; j < 4; ++j) {                             \
      st[j] = st[j] * 0.8f + tot[j] * 0.2f;                                     \
      hres[j] = fmaxf(st[j], 0.f);                                              \
    }                                                                           \
    unsigned long long hp = pack4bf(hres) | (((t >> 1) & 1) ? SMASK : 0ull);    \
    __hip_atomic_store(                                                         \
        (unsigned long long*)(hb[p] + (size_t)(b0 + pr) * H_DIM + h0 + pc), hp, \
        __ATOMIC_RELAXED, __HIP_MEMORY_SCOPE_AGENT);                            \
    asm volatile("s_barrier" ::: "memory");                                     \
    if (tid == 0)                                                               \
      __hip_atomic_store(myslot, (unsigned)(t + 1), __ATOMIC_RELAXED,           \
                         __HIP_MEMORY_SCOPE_AGENT);                             \
    *(f4_t*)(act + ((size_t)t * B_DIM + b0 + pr) * H_DIM + h0 + pc) = hres;     \
    ucur = unext;                                                               \
  }

  if (fast) {
    for (int t = 0; t < T_DIM; ++t) SCAN_STEP("sc0");
  } else {
    for (int t = 0; t < T_DIM; ++t) SCAN_STEP("sc0 sc1");
  }
#undef SCAN_STEP
#undef RELOAD
#undef STALE
}

// ------------------------------------------------- phase 3: act @ Wo^T + bo -
__global__ __launch_bounds__(256, 2) void k_outproj(
    const float* __restrict__ act, const unsigned short* __restrict__ Wo_b,
    const float* __restrict__ bo, float* __restrict__ out) {
  __shared__ unsigned short As[128 * 64];
  __shared__ unsigned short Bs[128 * 64];
  int m0 = blockIdx.x * 128;
  int tid = threadIdx.x;
  int lane = tid & 63, w = tid >> 6;
  int wm0 = (w & 1) * 64, wn0 = (w >> 1) * 64;
  int lrow = lane & 15, lk = (lane >> 4) * 8;
  f4_t acc[4][4];
#pragma unroll
  for (int a = 0; a < 4; ++a)
#pragma unroll
    for (int b = 0; b < 4; ++b) acc[a][b] = (f4_t){0.f, 0.f, 0.f, 0.f};

  for (int kb = 0; kb < 16; ++kb) {
    if (kb) __syncthreads();
#pragma unroll
    for (int it = 0; it < 8; ++it) {
      int c = it * 256 + tid;
      int row = c >> 4;
      int kc = (c & 15) * 4;
      f4_t v = *(const f4_t*)(act + (size_t)(m0 + row) * H_DIM + kb * 64 + kc);
      *(unsigned long long*)((char*)As + SWZ(row, row * 128 + kc * 2)) = pack4bf(v);
    }
#pragma unroll
    for (int it = 0; it < 4; ++it) {
      int c = it * 256 + tid;
      int row = c >> 3;
      int k16 = c & 7;
      u32x4 v = *(const u32x4*)(Wo_b + (size_t)row * H_DIM + kb * 64 + k16 * 8);
      *(u32x4*)((char*)Bs + SWZ(row, row * 128 + k16 * 16)) = v;
    }
    __syncthreads();
#pragma unroll
    for (int ks = 0; ks < 2; ++ks) {
      bf8_t aF[4], bF[4];
#pragma unroll
      for (int mt = 0; mt < 4; ++mt) {
        int row = wm0 + mt * 16 + lrow;
        aF[mt] = *(const bf8_t*)((char*)As + SWZ(row, row * 128 + (ks * 32 + lk) * 2));
      }
#pragma unroll
      for (int nt = 0; nt < 4; ++nt) {
        int row = wn0 + nt * 16 + lrow;
        bF[nt] = *(const bf8_t*)((char*)Bs + SWZ(row, row * 128 + (ks * 32 + lk) * 2));
      }
#pragma unroll
      for (int mt = 0; mt < 4; ++mt)
#pragma unroll
        for (int nt = 0; nt < 4; ++nt)
          acc[mt][nt] =
              __builtin_amdgcn_mfma_f32_16x16x32_bf16(aF[mt], bF[nt], acc[mt][nt], 0, 0, 0);
    }
  }
#pragma unroll
  for (int nt = 0; nt < 4; ++nt) {
    int col = wn0 + nt * 16 + lrow;
    float bv = bo[col];
#pragma unroll
    for (int mt = 0; mt < 4; ++mt) {
      int rbase = m0 + wm0 + mt * 16 + (lane >> 4) * 4;
#pragma unroll
      for (int r = 0; r < 4; ++r)
        out[(size_t)(rbase + r) * O_DIM + col] = acc[mt][nt][r] + bv;
    }
  }
}

// ---------------------------------------------------------------------------
extern "C" void kernel_launch(void* const* d_in, const int* in_sizes, int n_in,
                              void* d_out, int out_size, void* d_ws, size_t ws_size,
                              hipStream_t stream) {
  const float* x  = (const float*)d_in[0];
  const float* Wi = (const float*)d_in[1];
  const float* bi = (const float*)d_in[2];
  const float* Wh = (const float*)d_in[3];
  const float* bh = (const float*)d_in[4];
  const float* Wo = (const float*)d_in[5];
  const float* bo = (const float*)d_in[6];

  float* out = (float*)d_out;                                  // [T,B,O]
  float* act = out + (size_t)T_DIM * B_DIM * O_DIM;            // [T,B,H]

  char* ws = (char*)d_ws;
  unsigned short* Wh_b  = (unsigned short*)(ws);                               // 2 MB
  unsigned short* Wi_b  = (unsigned short*)(ws + (2u << 20));                  // 512 KB
  unsigned short* Wo_b  = (unsigned short*)(ws + (2u << 20) + (512u << 10));   // 256 KB
  unsigned short* hbuf0 = (unsigned short*)(ws + (2u << 20) + (768u << 10));   // 512 KB
  unsigned short* hbuf1 = (unsigned short*)(ws + (2u << 20) + (1280u << 10));  // 512 KB
  unsigned* done        = (unsigned*)(ws + (2u << 20) + (1792u << 10));        // 32 KB

  k_init<<<1024, 256, 0, stream>>>(Wi, Wh, Wo, Wi_b, Wh_b, Wo_b, hbuf1, done);
  k_inproj<<<8192, 256, 0, stream>>>(x, Wi_b, bi, act);
  k_scan<<<256, 256, 0, stream>>>(Wh_b, bh, act, hbuf0, hbuf1, done);
  k_outproj<<<1024, 256, 0, stream>>>(act, Wo_b, bo, out);
}